// Round 1
// baseline (42.517 us; speedup 1.0000x reference)
//
#include <hip/hip_runtime.h>

struct Cx { float r, i; };

// o = a*h + c   (complex fused multiply-add, 4 FMA)
__device__ __forceinline__ Cx cmadd(Cx a, Cx h, Cx c) {
    Cx o;
    o.r = fmaf(a.r, h.r, fmaf(-a.i, h.i, c.r));
    o.i = fmaf(a.r, h.i, fmaf(a.i, h.r, c.i));
    return o;
}

// degree-4/4 Pade rational: P(h)/Q(h), Q has implicit +1 constant term
__device__ __forceinline__ Cx pade(Cx h, const Cx A[5], const Cx Q[4]) {
    Cx num = A[4];
    num = cmadd(num, h, A[3]);
    num = cmadd(num, h, A[2]);
    num = cmadd(num, h, A[1]);
    num = cmadd(num, h, A[0]);
    Cx den = Q[3];
    den = cmadd(den, h, Q[2]);
    den = cmadd(den, h, Q[1]);
    den = cmadd(den, h, Q[0]);
    den = cmadd(den, h, Cx{1.0f, 0.0f});
    // num/den = num*conj(den) / |den|^2
    float inv = 1.0f / fmaf(den.r, den.r, den.i * den.i);
    Cx o;
    o.r = fmaf(num.r, den.r,  num.i * den.i) * inv;
    o.i = fmaf(num.i, den.r, -num.r * den.i) * inv;
    return o;
}

__global__ __launch_bounds__(256) void pade_model_kernel(
    const float2* __restrict__ x,
    const float* __restrict__ W1r, const float* __restrict__ W1i,
    const float* __restrict__ b1r, const float* __restrict__ b1i,
    const float* __restrict__ W2r, const float* __restrict__ W2i,
    const float* __restrict__ b2r, const float* __restrict__ b2i,
    const float* __restrict__ W3r, const float* __restrict__ W3i,
    const float* __restrict__ b3r, const float* __restrict__ b3i,
    const float* __restrict__ a1r, const float* __restrict__ a1i,
    const float* __restrict__ q1r, const float* __restrict__ q1i,
    const float* __restrict__ a2r, const float* __restrict__ a2i,
    const float* __restrict__ q2r, const float* __restrict__ q2i,
    float2* __restrict__ out, int n)
{
    int idx = blockIdx.x * blockDim.x + threadIdx.x;
    if (idx >= n) return;

    // ---- shared (wave-uniform) coefficients ----
    Cx A1[5], Q1[4], A2[5], Q2[4];
    #pragma unroll
    for (int j = 0; j < 5; ++j) { A1[j] = {a1r[j], a1i[j]}; A2[j] = {a2r[j], a2i[j]}; }
    #pragma unroll
    for (int j = 0; j < 4; ++j) { Q1[j] = {q1r[j], q1i[j]}; Q2[j] = {q2r[j], q2i[j]}; }

    // ---- fugacity: z = exp(mu_r) * (cos(mu_i) + i sin(mu_i)) ----
    float2 xv = x[idx];
    float er = expf(xv.x);
    float s, c;
    sincosf(xv.y, &s, &c);
    Cx z{er * c, er * s};

    // ---- layer 1: 1 -> 8 complex dense + pade ----
    Cx h1[8];
    #pragma unroll
    for (int j = 0; j < 8; ++j) {
        Cx w{W1r[j], W1i[j]};
        Cx b{b1r[j], b1i[j]};
        h1[j] = pade(cmadd(z, w, b), A1, Q1);
    }

    // ---- layer 2: 8 -> 4 complex dense + pade ----
    Cx h2[4];
    #pragma unroll
    for (int k = 0; k < 4; ++k) h2[k] = {b2r[k], b2i[k]};
    #pragma unroll
    for (int j = 0; j < 8; ++j) {
        #pragma unroll
        for (int k = 0; k < 4; ++k) {
            Cx w{W2r[j * 4 + k], W2i[j * 4 + k]};
            h2[k] = cmadd(h1[j], w, h2[k]);
        }
    }
    #pragma unroll
    for (int k = 0; k < 4; ++k) h2[k] = pade(h2[k], A2, Q2);

    // ---- layer 3: 4 -> 1 complex dense ----
    Cx o{b3r[0], b3i[0]};
    #pragma unroll
    for (int k = 0; k < 4; ++k) {
        Cx w{W3r[k], W3i[k]};
        o = cmadd(h2[k], w, o);
    }

    out[idx] = {o.r, o.i};
}

extern "C" void kernel_launch(void* const* d_in, const int* in_sizes, int n_in,
                              void* d_out, int out_size, void* d_ws, size_t ws_size,
                              hipStream_t stream) {
    // setup_inputs() dict order:
    // 0:x 1:W1r 2:W1i 3:b1r 4:b1i 5:W2r 6:W2i 7:b2r 8:b2i
    // 9:W3r 10:W3i 11:b3r 12:b3i 13:a1r 14:a1i 15:q1r 16:q1i
    // 17:a2r 18:a2i 19:q2r 20:q2i
    const float2* x  = (const float2*)d_in[0];
    const float* W1r = (const float*)d_in[1];
    const float* W1i = (const float*)d_in[2];
    const float* b1r = (const float*)d_in[3];
    const float* b1i = (const float*)d_in[4];
    const float* W2r = (const float*)d_in[5];
    const float* W2i = (const float*)d_in[6];
    const float* b2r = (const float*)d_in[7];
    const float* b2i = (const float*)d_in[8];
    const float* W3r = (const float*)d_in[9];
    const float* W3i = (const float*)d_in[10];
    const float* b3r = (const float*)d_in[11];
    const float* b3i = (const float*)d_in[12];
    const float* a1r = (const float*)d_in[13];
    const float* a1i = (const float*)d_in[14];
    const float* q1r = (const float*)d_in[15];
    const float* q1i = (const float*)d_in[16];
    const float* a2r = (const float*)d_in[17];
    const float* a2i = (const float*)d_in[18];
    const float* q2r = (const float*)d_in[19];
    const float* q2i = (const float*)d_in[20];

    int n = in_sizes[0] / 2;  // number of samples (x is [B,2])
    float2* out = (float2*)d_out;

    dim3 block(256);
    dim3 grid((n + 255) / 256);
    pade_model_kernel<<<grid, block, 0, stream>>>(
        x, W1r, W1i, b1r, b1i, W2r, W2i, b2r, b2i, W3r, W3i, b3r, b3i,
        a1r, a1i, q1r, q1i, a2r, a2i, q2r, q2i, out, n);
}

// Round 2
// 33.976 us; speedup vs baseline: 1.2514x; 1.2514x over previous
//
#include <hip/hip_runtime.h>

typedef float f32x2 __attribute__((ext_vector_type(2)));

// complex fused multiply-add: a*h + c  (2 packed FMAs)
// o.r = a.r*h.r - a.i*h.i + c.r
// o.i = a.r*h.i + a.i*h.r + c.i
__device__ __forceinline__ f32x2 cfma(f32x2 a, f32x2 h, f32x2 c) {
    f32x2 ar = {a.x, a.x};
    f32x2 ai = {a.y, a.y};
    f32x2 hs = {-h.y, h.x};
    return __builtin_elementwise_fma(ai, hs, __builtin_elementwise_fma(ar, h, c));
}

// degree-4/4 Pade rational P(h)/Q(h), Q has implicit +1 constant term
__device__ __forceinline__ f32x2 pade(f32x2 h, const f32x2 A[5], const f32x2 Q[4]) {
    f32x2 num = A[4];
    num = cfma(num, h, A[3]);
    num = cfma(num, h, A[2]);
    num = cfma(num, h, A[1]);
    num = cfma(num, h, A[0]);
    f32x2 den = Q[3];
    den = cfma(den, h, Q[2]);
    den = cfma(den, h, Q[1]);
    den = cfma(den, h, Q[0]);
    den = cfma(den, h, f32x2{1.0f, 0.0f});
    // num/den = num*conj(den) * rcp(|den|^2)
    float d2  = fmaf(den.x, den.x, den.y * den.y);
    float inv = __builtin_amdgcn_rcpf(d2);
    f32x2 dr = {den.x, den.x};
    f32x2 di = {den.y, den.y};
    f32x2 ns = {num.y, -num.x};
    f32x2 t  = __builtin_elementwise_fma(ns, di, num * dr);
    return t * f32x2{inv, inv};
}

__global__ __launch_bounds__(256) void pade_model_kernel(
    const float2* __restrict__ x,
    const float* __restrict__ W1r, const float* __restrict__ W1i,
    const float* __restrict__ b1r, const float* __restrict__ b1i,
    const float* __restrict__ W2r, const float* __restrict__ W2i,
    const float* __restrict__ b2r, const float* __restrict__ b2i,
    const float* __restrict__ W3r, const float* __restrict__ W3i,
    const float* __restrict__ b3r, const float* __restrict__ b3i,
    const float* __restrict__ a1r, const float* __restrict__ a1i,
    const float* __restrict__ q1r, const float* __restrict__ q1i,
    const float* __restrict__ a2r, const float* __restrict__ a2i,
    const float* __restrict__ q2r, const float* __restrict__ q2i,
    float2* __restrict__ out, int n)
{
    int idx = blockIdx.x * blockDim.x + threadIdx.x;
    if (idx >= n) return;

    // ---- wave-uniform coefficients (SGPR-resident) ----
    f32x2 A1[5], Q1[4], A2[5], Q2[4];
    #pragma unroll
    for (int j = 0; j < 5; ++j) { A1[j] = {a1r[j], a1i[j]}; A2[j] = {a2r[j], a2i[j]}; }
    #pragma unroll
    for (int j = 0; j < 4; ++j) { Q1[j] = {q1r[j], q1i[j]}; Q2[j] = {q2r[j], q2i[j]}; }

    // ---- fugacity: z = exp(mu_r) * (cos(mu_i) + i sin(mu_i)) ----
    // |x| <= ~1.6 rad -> native-range safe for v_exp/v_sin/v_cos
    float2 xv = x[idx];
    float er = __expf(xv.x);
    float s  = __sinf(xv.y);
    float c  = __cosf(xv.y);
    f32x2 z = f32x2{c, s} * er;

    // ---- layer 1: 1 -> 8 complex dense + pade ----
    f32x2 h1[8];
    #pragma unroll
    for (int j = 0; j < 8; ++j) {
        f32x2 w = {W1r[j], W1i[j]};
        f32x2 b = {b1r[j], b1i[j]};
        h1[j] = pade(cfma(z, w, b), A1, Q1);
    }

    // ---- layer 2: 8 -> 4 complex dense + pade ----
    f32x2 h2[4];
    #pragma unroll
    for (int k = 0; k < 4; ++k) h2[k] = {b2r[k], b2i[k]};
    #pragma unroll
    for (int j = 0; j < 8; ++j) {
        #pragma unroll
        for (int k = 0; k < 4; ++k) {
            f32x2 w = {W2r[j * 4 + k], W2i[j * 4 + k]};
            h2[k] = cfma(h1[j], w, h2[k]);
        }
    }
    #pragma unroll
    for (int k = 0; k < 4; ++k) h2[k] = pade(h2[k], A2, Q2);

    // ---- layer 3: 4 -> 1 complex dense ----
    f32x2 o = {b3r[0], b3i[0]};
    #pragma unroll
    for (int k = 0; k < 4; ++k) {
        f32x2 w = {W3r[k], W3i[k]};
        o = cfma(h2[k], w, o);
    }

    out[idx] = {o.x, o.y};
}

extern "C" void kernel_launch(void* const* d_in, const int* in_sizes, int n_in,
                              void* d_out, int out_size, void* d_ws, size_t ws_size,
                              hipStream_t stream) {
    // setup_inputs() dict order:
    // 0:x 1:W1r 2:W1i 3:b1r 4:b1i 5:W2r 6:W2i 7:b2r 8:b2i
    // 9:W3r 10:W3i 11:b3r 12:b3i 13:a1r 14:a1i 15:q1r 16:q1i
    // 17:a2r 18:a2i 19:q2r 20:q2i
    const float2* x  = (const float2*)d_in[0];
    const float* W1r = (const float*)d_in[1];
    const float* W1i = (const float*)d_in[2];
    const float* b1r = (const float*)d_in[3];
    const float* b1i = (const float*)d_in[4];
    const float* W2r = (const float*)d_in[5];
    const float* W2i = (const float*)d_in[6];
    const float* b2r = (const float*)d_in[7];
    const float* b2i = (const float*)d_in[8];
    const float* W3r = (const float*)d_in[9];
    const float* W3i = (const float*)d_in[10];
    const float* b3r = (const float*)d_in[11];
    const float* b3i = (const float*)d_in[12];
    const float* a1r = (const float*)d_in[13];
    const float* a1i = (const float*)d_in[14];
    const float* q1r = (const float*)d_in[15];
    const float* q1i = (const float*)d_in[16];
    const float* a2r = (const float*)d_in[17];
    const float* a2i = (const float*)d_in[18];
    const float* q2r = (const float*)d_in[19];
    const float* q2i = (const float*)d_in[20];

    int n = in_sizes[0] / 2;  // number of samples (x is [B,2])
    float2* out = (float2*)d_out;

    dim3 block(256);
    dim3 grid((n + 255) / 256);
    pade_model_kernel<<<grid, block, 0, stream>>>(
        x, W1r, W1i, b1r, b1i, W2r, W2i, b2r, b2i, W3r, W3i, b3r, b3i,
        a1r, a1i, q1r, q1i, a2r, a2i, q2r, q2i, out, n);
}